// Round 2
// baseline (27802.313 us; speedup 1.0000x reference)
//
#include <hip/hip_runtime.h>
#include <hip/hip_bf16.h>
#include <cstdint>

// PhaseEncodingSNN: B=64, T=512, I=256, H=512, O=256.
// R6 change: k_recurrent_cp exchange moved from LLC (agent-scope atomics,
// sc1 = L2-bypass on multi-XCD gfx950) to the shared per-XCD L2:
//  - runtime XCC_ID consensus (HW_REG_XCC_ID, m09): group members verify they
//    share an XCD; unanimous -> fast path, else full agent-scope fallback.
//  - fast path: producers PLAIN-store mem (dirty in shared L2, ~150cy);
//    consumers poll with inline-asm `global_load_dword ... sc0` (L1-bypass,
//    L2-served, ~250cy).  Escalates to `sc0 sc1` after 512 tries (guaranteed
//    progress even if sc0-alone semantics differ), s_sleep after 8192.
//  - all arithmetic bit-identical to R5 (FMA order, swizzle reduce, LIF).
// R5 scan structure retained: transposed mapping, 1 barrier/step, parity
// double-buffered padded memLDS, mem in registers, swizzle reduce.
// GEMMs / LIF1 / softmax / attend unchanged.

#define T_STEPS 512
#define BATCH 64
#define HID 512
#define IN_DIM 256
#define OUT_DIM 256
#define BETA 0.9f
#define THR 1.0f
#define SENT 0x7FC00000u

typedef __attribute__((ext_vector_type(8))) short short8;
typedef __attribute__((ext_vector_type(4))) float float4v;
typedef unsigned short ushort_t;

// ---------------------------------------------------------------- NaN fill
__global__ __launch_bounds__(256) void k_fill_nan(uint32_t* __restrict__ P,
                                                  uint32_t* __restrict__ xcc) {
  const int idx = blockIdx.x * 256 + threadIdx.x;  // 65536 threads
  uint4 s = make_uint4(SENT, SENT, SENT, SENT);
  uint4* p4 = (uint4*)P;
  for (int i = idx; i < (32768 * 512) / 4; i += 65536) p4[i] = s;
  if (idx < 256) xcc[idx] = SENT;
}

// ---------------------------------------------------------------- fp32 -> hi/lo bf16 split
__global__ __launch_bounds__(256) void k_split(const float* __restrict__ src,
                                               ushort_t* __restrict__ hi,
                                               ushort_t* __restrict__ lo, int n) {
  int i = blockIdx.x * 256 + threadIdx.x;
  const int stride = gridDim.x * 256;
  for (; i < n; i += stride) {
    float v = src[i];
    uint32_t u = __float_as_uint(v);
    uint32_t rh = u + 0x7FFFu + ((u >> 16) & 1u);   // RNE to bf16
    ushort_t h = (ushort_t)(rh >> 16);
    float hf = __uint_as_float(((uint32_t)h) << 16);
    float l = v - hf;
    uint32_t ul = __float_as_uint(l);
    uint32_t rl = ul + 0x7FFFu + ((ul >> 16) & 1u);
    hi[i] = h;
    lo[i] = (ushort_t)(rl >> 16);
  }
}

// ---------------------------------------------------------------- softmax over t
__global__ __launch_bounds__(256) void k_softmax_t(
    const float* __restrict__ TA, float* __restrict__ attn) {
  __shared__ float redm[8][32];
  __shared__ float reds[8][32];
  const int ol = threadIdx.x & 31;
  const int tg = threadIdx.x >> 5;
  const int o = blockIdx.x * 32 + ol;
  float mx = -1e30f;
  for (int i = 0; i < 64; ++i) {
    float v = TA[(size_t)(tg * 64 + i) * OUT_DIM + o];
    mx = fmaxf(mx, v);
  }
  redm[tg][ol] = mx;
  __syncthreads();
  float m = redm[0][ol];
#pragma unroll
  for (int j = 1; j < 8; ++j) m = fmaxf(m, redm[j][ol]);
  float s = 0.f;
  for (int i = 0; i < 64; ++i) {
    float v = TA[(size_t)(tg * 64 + i) * OUT_DIM + o];
    s += __expf(v - m);
  }
  reds[tg][ol] = s;
  __syncthreads();
  float tot = 0.f;
#pragma unroll
  for (int j = 0; j < 8; ++j) tot += reds[j][ol];
  const float inv = 1.0f / tot;
  for (int i = 0; i < 64; ++i) {
    int t = tg * 64 + i;
    float v = TA[(size_t)t * OUT_DIM + o];
    attn[(size_t)t * OUT_DIM + o] = __expf(v - m) * inv;
  }
}

// ---------------------------------------------------------------- MFMA GEMM, 3-term split
__global__ __launch_bounds__(256) void k_gemm_split3(
    const ushort_t* __restrict__ Ahi, const ushort_t* __restrict__ Alo,
    const ushort_t* __restrict__ Bhi, const ushort_t* __restrict__ Blo,
    const float* __restrict__ bias, float* __restrict__ C,
    int M, int N, int K) {
  __shared__ ushort_t At[2][128 * 40];
  __shared__ ushort_t Bt[2][128 * 40];
  const int tid = threadIdx.x;
  const int row0 = blockIdx.x * 128, col0 = blockIdx.y * 128;
  const int w = tid >> 6, lane = tid & 63;
  const int wm = (w >> 1) * 64, wn = (w & 1) * 64;
  const int l15 = lane & 15, quad = lane >> 4;
  float4v acc[4][4];
#pragma unroll
  for (int i = 0; i < 4; ++i)
#pragma unroll
    for (int j = 0; j < 4; ++j) acc[i][j] = (float4v){0.f, 0.f, 0.f, 0.f};

  for (int k0 = 0; k0 < K; k0 += 32) {
#pragma unroll
    for (int it = 0; it < 2; ++it) {
      int idx = it * 256 + tid;          // 0..511
      int r = idx >> 2;                  // row 0..127
      int c8 = (idx & 3) << 3;           // k-offset {0,8,16,24}
      *(uint4*)(&At[0][r * 40 + c8]) =
          *(const uint4*)(&Ahi[(size_t)(row0 + r) * K + k0 + c8]);
      *(uint4*)(&At[1][r * 40 + c8]) =
          *(const uint4*)(&Alo[(size_t)(row0 + r) * K + k0 + c8]);
      *(uint4*)(&Bt[0][r * 40 + c8]) =
          *(const uint4*)(&Bhi[(size_t)(col0 + r) * K + k0 + c8]);
      *(uint4*)(&Bt[1][r * 40 + c8]) =
          *(const uint4*)(&Blo[(size_t)(col0 + r) * K + k0 + c8]);
    }
    __syncthreads();
    short8 ah[4], al[4], bh[4], bl[4];
    const int koff = quad * 8;
#pragma unroll
    for (int i = 0; i < 4; ++i) {
      ah[i] = *(const short8*)(&At[0][(wm + i * 16 + l15) * 40 + koff]);
      al[i] = *(const short8*)(&At[1][(wm + i * 16 + l15) * 40 + koff]);
      bh[i] = *(const short8*)(&Bt[0][(wn + i * 16 + l15) * 40 + koff]);
      bl[i] = *(const short8*)(&Bt[1][(wn + i * 16 + l15) * 40 + koff]);
    }
#pragma unroll
    for (int i = 0; i < 4; ++i)
#pragma unroll
      for (int j = 0; j < 4; ++j) {
        acc[i][j] = __builtin_amdgcn_mfma_f32_16x16x32_bf16(ah[i], bh[j], acc[i][j], 0, 0, 0);
        acc[i][j] = __builtin_amdgcn_mfma_f32_16x16x32_bf16(ah[i], bl[j], acc[i][j], 0, 0, 0);
        acc[i][j] = __builtin_amdgcn_mfma_f32_16x16x32_bf16(al[i], bh[j], acc[i][j], 0, 0, 0);
      }
    __syncthreads();
  }
#pragma unroll
  for (int j = 0; j < 4; ++j) {
    const int col = col0 + wn + j * 16 + l15;
    const float bv = bias ? bias[col] : 0.f;
#pragma unroll
    for (int i = 0; i < 4; ++i) {
#pragma unroll
      for (int r = 0; r < 4; ++r) {
        int row = row0 + wm + i * 16 + quad * 4 + r;
        C[(size_t)row * N + col] = acc[i][j][r] + bv;
      }
    }
  }
}

// ---------------------------------------------------------------- MFMA GEMM, spike-A 2-term
__global__ __launch_bounds__(256) void k_gemm_spike2(
    const float* __restrict__ A, const ushort_t* __restrict__ Bhi,
    const ushort_t* __restrict__ Blo, const float* __restrict__ bias,
    float* __restrict__ C, int M, int N, int K) {
  __shared__ ushort_t At[128 * 72];
  __shared__ ushort_t Bt[2][128 * 72];
  const int tid = threadIdx.x;
  const int row0 = blockIdx.x * 128, col0 = blockIdx.y * 128;
  const int w = tid >> 6, lane = tid & 63;
  const int wm = (w >> 1) * 64, wn = (w & 1) * 64;
  const int l15 = lane & 15, quad = lane >> 4;
  float4v acc[4][4];
#pragma unroll
  for (int i = 0; i < 4; ++i)
#pragma unroll
    for (int j = 0; j < 4; ++j) acc[i][j] = (float4v){0.f, 0.f, 0.f, 0.f};

  for (int k0 = 0; k0 < K; k0 += 64) {
#pragma unroll
    for (int it = 0; it < 4; ++it) {
      int idx = it * 256 + tid;          // 0..1023
      int r = idx >> 3;                  // row 0..127
      int c8 = (idx & 7) << 3;           // k-offset 0..56 step 8
      uint4 pa = *(const uint4*)(&A[(size_t)(row0 + r) * K + k0 + c8]);
      uint4 pb = *(const uint4*)(&A[(size_t)(row0 + r) * K + k0 + c8 + 4]);
      uint4 st;
      st.x = (pa.x >> 16) | (pa.y & 0xFFFF0000u);
      st.y = (pa.z >> 16) | (pa.w & 0xFFFF0000u);
      st.z = (pb.x >> 16) | (pb.y & 0xFFFF0000u);
      st.w = (pb.z >> 16) | (pb.w & 0xFFFF0000u);
      *(uint4*)(&At[r * 72 + c8]) = st;
      *(uint4*)(&Bt[0][r * 72 + c8]) =
          *(const uint4*)(&Bhi[(size_t)(col0 + r) * K + k0 + c8]);
      *(uint4*)(&Bt[1][r * 72 + c8]) =
          *(const uint4*)(&Blo[(size_t)(col0 + r) * K + k0 + c8]);
    }
    __syncthreads();
#pragma unroll
    for (int ks = 0; ks < 2; ++ks) {
      short8 a[4], bh[4], bl[4];
      const int koff = ks * 32 + quad * 8;
#pragma unroll
      for (int i = 0; i < 4; ++i) {
        a[i] = *(const short8*)(&At[(wm + i * 16 + l15) * 72 + koff]);
        bh[i] = *(const short8*)(&Bt[0][(wn + i * 16 + l15) * 72 + koff]);
        bl[i] = *(const short8*)(&Bt[1][(wn + i * 16 + l15) * 72 + koff]);
      }
#pragma unroll
      for (int i = 0; i < 4; ++i)
#pragma unroll
        for (int j = 0; j < 4; ++j) {
          acc[i][j] = __builtin_amdgcn_mfma_f32_16x16x32_bf16(a[i], bh[j], acc[i][j], 0, 0, 0);
          acc[i][j] = __builtin_amdgcn_mfma_f32_16x16x32_bf16(a[i], bl[j], acc[i][j], 0, 0, 0);
        }
    }
    __syncthreads();
  }
#pragma unroll
  for (int j = 0; j < 4; ++j) {
    const int col = col0 + wn + j * 16 + l15;
    const float bv = bias ? bias[col] : 0.f;
#pragma unroll
    for (int i = 0; i < 4; ++i) {
#pragma unroll
      for (int r = 0; r < 4; ++r) {
        int row = row0 + wm + i * 16 + quad * 4 + r;
        C[(size_t)row * N + col] = acc[i][j][r] + bv;
      }
    }
  }
}

// ---------------------------------------------------------------- LIF scan #1
__global__ __launch_bounds__(256) void k_lif1(float* __restrict__ p) {
  const int id = blockIdx.x * 256 + threadIdx.x;  // 0..32767
  const size_t base = (size_t)(id >> 9) * (T_STEPS * HID) + (id & 511);
  float mem = 0.f;
  for (int t0 = 0; t0 < T_STEPS; t0 += 8) {
    float v[8];
#pragma unroll
    for (int j = 0; j < 8; ++j) v[j] = p[base + (size_t)(t0 + j) * HID];
#pragma unroll
    for (int j = 0; j < 8; ++j) {
      float nm = BETA * mem + v[j];
      float sp = nm > THR ? 1.0f : 0.0f;
      p[base + (size_t)(t0 + j) * HID] = sp;
      mem = nm - sp;
    }
  }
}

// ---------------------------------------------------------------- recurrent scan core (R6)
// FASTP=true: same-XCD verified; plain stores (dirty in shared L2) + sc0 polls
// (L1-bypass, L2-served).  Escalation: >512 tries -> sc0 sc1 (system scope,
// L2-in-path dirty-hit service: guaranteed progress), >8192 -> s_sleep.
// FASTP=false: original agent-scope (LLC) protocol.
template <bool FASTP>
__device__ __forceinline__ void rec_scan(
    const int tid, const int grp, const int j, const int c, const int row,
    const bool lif, const int og, const int rg, const int raddr,
    const size_t rp_b0, const size_t rp_b1, const float bhh_v,
    const float (&Wreg)[64], float (&memLDS)[2][2][8 * 72],
    float* rp, float* P) {
  const uint32_t* Pu = (const uint32_t*)P;
  float mem0 = 0.f, mem1 = 0.f;
  for (int t = 0; t < T_STEPS; ++t) {
    const int par = t & 1;
    float ip0 = 0.f, ip1 = 0.f;
    if (lif) {
      ip0 = rp[rp_b0 + (size_t)t * HID];
      ip1 = rp[rp_b1 + (size_t)t * HID];
    }
    if (t > 0 && tid < 448) {
      const size_t slot = ((size_t)(t - 1) * 32 + grp) * 1024;
      const uint32_t* a0p = Pu + slot + rg;
      const uint32_t* a1p = a0p + 512;
      uint32_t u0, u1;
      int tries = 0;
      for (;;) {
        if (FASTP) {
          if (tries < 512) {
            asm volatile("global_load_dword %0, %2, off sc0\n\t"
                         "global_load_dword %1, %3, off sc0\n\t"
                         "s_waitcnt vmcnt(0)"
                         : "=&v"(u0), "=&v"(u1)
                         : "v"(a0p), "v"(a1p)
                         : "memory");
          } else {
            asm volatile("global_load_dword %0, %2, off sc0 sc1\n\t"
                         "global_load_dword %1, %3, off sc0 sc1\n\t"
                         "s_waitcnt vmcnt(0)"
                         : "=&v"(u0), "=&v"(u1)
                         : "v"(a0p), "v"(a1p)
                         : "memory");
          }
        } else {
          u0 = __hip_atomic_load(a0p, __ATOMIC_RELAXED, __HIP_MEMORY_SCOPE_AGENT);
          u1 = __hip_atomic_load(a1p, __ATOMIC_RELAXED, __HIP_MEMORY_SCOPE_AGENT);
        }
        if (u0 != SENT && u1 != SENT) break;
        ++tries;
        if (tries > 8192) __builtin_amdgcn_s_sleep(1);
      }
      memLDS[par][0][raddr] = __uint_as_float(u0);
      memLDS[par][1][raddr] = __uint_as_float(u1);
    }
    __syncthreads();

    float p0a = 0.f, p0b = 0.f, p1a = 0.f, p1b = 0.f;
    {
      const float4* m0 = (const float4*)&memLDS[par][0][c * 72];
      const float4* m1 = (const float4*)&memLDS[par][1][c * 72];
#pragma unroll
      for (int k4 = 0; k4 < 16; ++k4) {
        float4 a = m0[k4];
        float4 b = m1[k4];
        p0a = fmaf(Wreg[4 * k4 + 0], a.x, p0a);
        p0b = fmaf(Wreg[4 * k4 + 1], a.y, p0b);
        p0a = fmaf(Wreg[4 * k4 + 2], a.z, p0a);
        p0b = fmaf(Wreg[4 * k4 + 3], a.w, p0b);
        p1a = fmaf(Wreg[4 * k4 + 0], b.x, p1a);
        p1b = fmaf(Wreg[4 * k4 + 1], b.y, p1b);
        p1a = fmaf(Wreg[4 * k4 + 2], b.z, p1a);
        p1b = fmaf(Wreg[4 * k4 + 3], b.w, p1b);
      }
    }
    const int i0 = __float_as_int(p0a + p0b);
    const int i1 = __float_as_int(p1a + p1b);
    // serial ascending-chunk reduce across lanes (l&56)+ss  (== old scratch)
    float s0 = 0.f, s1 = 0.f;
#define RED(ss)                                                                 \
    s0 += __int_as_float(__builtin_amdgcn_ds_swizzle(i0, ((ss) << 5) | 0x18)); \
    s1 += __int_as_float(__builtin_amdgcn_ds_swizzle(i1, ((ss) << 5) | 0x18));
    RED(0) RED(1) RED(2) RED(3) RED(4) RED(5) RED(6) RED(7)
#undef RED

    if (lif) {
      const int npar = par ^ 1;
      const size_t slot = ((size_t)t * 32 + grp) * 1024;
      const float nm0 = BETA * mem0 + ip0 + s0 + bhh_v;
      const float sp0 = nm0 > THR ? 1.0f : 0.0f;
      mem0 = nm0 - sp0;
      if (FASTP)
        P[slot + og] = mem0;
      else
        __hip_atomic_store(P + slot + og, mem0, __ATOMIC_RELAXED,
                           __HIP_MEMORY_SCOPE_AGENT);
      const float nm1 = BETA * mem1 + ip1 + s1 + bhh_v;
      const float sp1 = nm1 > THR ? 1.0f : 0.0f;
      mem1 = nm1 - sp1;
      if (FASTP)
        P[slot + 512 + og] = mem1;
      else
        __hip_atomic_store(P + slot + 512 + og, mem1, __ATOMIC_RELAXED,
                           __HIP_MEMORY_SCOPE_AGENT);
      rp[rp_b0 + (size_t)t * HID] = sp0;
      rp[rp_b1 + (size_t)t * HID] = sp1;
      memLDS[npar][0][j * 72 + row] = mem0;
      memLDS[npar][1][j * 72 + row] = mem1;
    }
  }
}

__global__ __launch_bounds__(512) void k_recurrent_cp(
    const float* __restrict__ W, const float* __restrict__ b_hh,
    float* __restrict__ rp, float* __restrict__ P,
    uint32_t* __restrict__ xcc) {
  const int tid = threadIdx.x;
  const int grp = blockIdx.x & 31;  // stride-32 members: same XCD under %8 RR
  const int j   = blockIdx.x >> 5;  // k-chunk / output-column block 0..7
  const int w   = tid >> 6;         // wave 0..7
  const int l   = tid & 63;
  const int q   = l >> 3;           // row-in-group 0..7
  const int c   = l & 7;            // k-chunk of this lane
  const int row = (w << 3) + q;     // 0..63 output row within block
  const int g0  = j << 6;

  __shared__ float memLDS[2][2][8 * 72];  // [parity][ob][chunk*72 + k]
  __shared__ uint32_t xcc_sh[8];

  // --- XCD consensus (agent-scope; xcc pre-filled with SENT by k_fill_nan)
  {
    uint32_t myx;
    asm volatile("s_getreg_b32 %0, hwreg(HW_REG_XCC_ID)" : "=s"(myx));
    if (tid == 0)
      __hip_atomic_store(&xcc[blockIdx.x], myx, __ATOMIC_RELAXED,
                         __HIP_MEMORY_SCOPE_AGENT);
    if (tid < 8) {
      uint32_t v;
      int tries = 0;
      do {
        v = __hip_atomic_load(&xcc[grp + 32 * tid], __ATOMIC_RELAXED,
                              __HIP_MEMORY_SCOPE_AGENT);
        if (++tries > 64) __builtin_amdgcn_s_sleep(1);
      } while (v == SENT);
      xcc_sh[tid] = v;
    }
  }

  for (int i = tid; i < 2 * 2 * 8 * 72; i += 512) ((float*)memLDS)[i] = 0.f;

  float Wreg[64];
  {
    const float* wrow = W + (size_t)(g0 + row) * HID + (c << 6);
#pragma unroll
    for (int k4 = 0; k4 < 16; ++k4) {
      float4 w4 = *(const float4*)(wrow + 4 * k4);
      Wreg[4 * k4 + 0] = w4.x; Wreg[4 * k4 + 1] = w4.y;
      Wreg[4 * k4 + 2] = w4.z; Wreg[4 * k4 + 3] = w4.w;
    }
  }

  const bool lif = (c == 0);
  const int og = g0 + row;
  const size_t rp_b0 = (size_t)(grp * 2 + 0) * (T_STEPS * HID) + og;
  const size_t rp_b1 = (size_t)(grp * 2 + 1) * (T_STEPS * HID) + og;
  const float bhh_v = lif ? b_hh[og] : 0.f;

  const int rg = (tid < g0) ? tid : tid + 64;        // remote k (tid<448)
  const int raddr = (rg >> 6) * 72 + (rg & 63);

  __syncthreads();

  bool same = true;
  {
    const uint32_t x0 = xcc_sh[0];
#pragma unroll
    for (int jj = 1; jj < 8; ++jj) same = same && (xcc_sh[jj] == x0);
  }

  if (same)
    rec_scan<true>(tid, grp, j, c, row, lif, og, rg, raddr, rp_b0, rp_b1,
                   bhh_v, Wreg, memLDS, rp, P);
  else
    rec_scan<false>(tid, grp, j, c, row, lif, og, rg, raddr, rp_b0, rp_b1,
                    bhh_v, Wreg, memLDS, rp, P);
}

// ---------------------------------------------------------------- attend + threshold
__global__ __launch_bounds__(256) void k_attend(
    const float* __restrict__ op, const float* __restrict__ attn,
    const float* __restrict__ b_out, float* __restrict__ out) {
  const int b = blockIdx.x;
  const int o = threadIdx.x;
  float s = b_out[o];
  const float* opb = op + (size_t)b * T_STEPS * OUT_DIM + o;
  for (int t0 = 0; t0 < T_STEPS; t0 += 8) {
    float av[8], pv[8];
#pragma unroll
    for (int j = 0; j < 8; ++j) {
      av[j] = attn[(size_t)(t0 + j) * OUT_DIM + o];
      pv[j] = opb[(size_t)(t0 + j) * OUT_DIM];
    }
#pragma unroll
    for (int j = 0; j < 8; ++j) s = fmaf(av[j], pv[j], s);
  }
  out[b * OUT_DIM + o] = s > THR ? 1.0f : 0.0f;
}

// ---------------------------------------------------------------- launch
extern "C" void kernel_launch(void* const* d_in, const int* in_sizes, int n_in,
                              void* d_out, int out_size, void* d_ws, size_t ws_size,
                              hipStream_t stream) {
  (void)in_sizes; (void)n_in; (void)out_size; (void)ws_size;
  const float* x     = (const float*)d_in[0];
  const float* W_in  = (const float*)d_in[1];
  const float* b_in  = (const float*)d_in[2];
  const float* W_ih  = (const float*)d_in[3];
  const float* b_ih  = (const float*)d_in[4];
  const float* W_hh  = (const float*)d_in[5];
  const float* b_hh  = (const float*)d_in[6];
  const float* W_out = (const float*)d_in[7];
  const float* b_out = (const float*)d_in[8];
  const float* TA    = (const float*)d_in[9];

  float* ws = (float*)d_ws;
  float* proj  = ws;                           // 16.78M floats: GEMM1 out / P / out_proj
  float* rproj = proj + (size_t)32768 * 512;   // 16.78M floats: x-splits, then GEMM2 out
  float* attn  = rproj + (size_t)32768 * 512;  // 131072 floats
  ushort_t* wih_hi = (ushort_t*)(attn + 512 * 256);
  ushort_t* wih_lo = wih_hi + 512 * 512;
  ushort_t* win_hi = wih_lo + 512 * 512;
  ushort_t* win_lo = win_hi + 512 * 256;
  ushort_t* wout_hi = win_lo + 512 * 256;
  ushort_t* wout_lo = wout_hi + 256 * 512;
  ushort_t* x_hi = (ushort_t*)rproj;
  ushort_t* x_lo = x_hi + (size_t)32768 * 256;
  float* P = proj;            // exchange slots [t][grp][ob][g]
  float* out_proj = proj;     // (b*T, O) fp32, written after recurrent
  // XCC consensus array aliases win_hi (dead after GEMM1, filled by k_fill_nan)
  uint32_t* xcc = (uint32_t*)win_hi;

  k_softmax_t<<<8, 256, 0, stream>>>(TA, attn);
  k_split<<<4096, 256, 0, stream>>>(x, x_hi, x_lo, 32768 * 256);
  k_split<<<512, 256, 0, stream>>>(W_in, win_hi, win_lo, 512 * 256);
  k_split<<<512, 256, 0, stream>>>(W_ih, wih_hi, wih_lo, 512 * 512);
  k_split<<<512, 256, 0, stream>>>(W_out, wout_hi, wout_lo, 256 * 512);

  // GEMM1: proj = x @ W_in^T + b_in   (M=32768, N=512, K=256)
  k_gemm_split3<<<dim3(256, 4), 256, 0, stream>>>(
      x_hi, x_lo, win_hi, win_lo, b_in, proj, 32768, 512, 256);
  k_lif1<<<128, 256, 0, stream>>>(proj);
  // GEMM2: rproj = spikes @ W_ih^T + b_ih   (M=32768, N=512, K=512)
  k_gemm_spike2<<<dim3(256, 4), 256, 0, stream>>>(
      proj, wih_hi, wih_lo, b_ih, rproj, 32768, 512, 512);
  k_fill_nan<<<256, 256, 0, stream>>>((uint32_t*)P, xcc);  // proj dead after GEMM2
  k_recurrent_cp<<<256, 512, 0, stream>>>(W_hh, b_hh, rproj, P, xcc);
  // GEMM3: out_proj = tspikes @ W_out^T   (M=32768, N=256, K=512, no bias)
  k_gemm_spike2<<<dim3(256, 2), 256, 0, stream>>>(
      rproj, wout_hi, wout_lo, nullptr, out_proj, 32768, 256, 512);
  k_attend<<<64, 256, 0, stream>>>(out_proj, attn, b_out, (float*)d_out);
}

// Round 3
// 1777.893 us; speedup vs baseline: 15.6378x; 15.6378x over previous
//
#include <hip/hip_runtime.h>
#include <hip/hip_bf16.h>
#include <cstdint>

// PhaseEncodingSNN: B=64, T=512, I=256, H=512, O=256.
// R7: k_recurrent_cp -> BARRIER-FREE free-running waves.
//  R6 lesson (26x regression): sc0 loads do NOT bypass L1 on gfx950; stale-L1
//  spin until system-scope escalation. Exchange semantics reverted to R5's
//  PROVEN agent-scope relaxed atomics.
//  R7 structure: each wave polls ALL 512 membrane rows itself (8 independent
//  qword atomic loads/lane, straggler-only retries), deposits into a
//  wave-PRIVATE LDS region, computes, in-wave swizzle-reduce. No __syncthreads
//  in the scan -> no barrier quantization on the slowest poll lane.
//  P layout: interleaved (mem0,mem1) qword pairs -> producer stores one 8B
//  atomic; consumer fetches both batches per load.
//  All FMA order / swizzle reduce / LIF arithmetic bitwise == R5.
// GEMMs / LIF1 / softmax / attend unchanged.

#define T_STEPS 512
#define BATCH 64
#define HID 512
#define IN_DIM 256
#define OUT_DIM 256
#define BETA 0.9f
#define THR 1.0f
#define SENT 0x7FC00000u

typedef __attribute__((ext_vector_type(8))) short short8;
typedef __attribute__((ext_vector_type(4))) float float4v;
typedef unsigned short ushort_t;

// ---------------------------------------------------------------- NaN fill
__global__ __launch_bounds__(256) void k_fill_nan(uint32_t* __restrict__ P) {
  const int idx = blockIdx.x * 256 + threadIdx.x;  // 65536 threads
  uint4 s = make_uint4(SENT, SENT, SENT, SENT);
  uint4* p4 = (uint4*)P;
  for (int i = idx; i < (32768 * 512) / 4; i += 65536) p4[i] = s;
}

// ---------------------------------------------------------------- fp32 -> hi/lo bf16 split
__global__ __launch_bounds__(256) void k_split(const float* __restrict__ src,
                                               ushort_t* __restrict__ hi,
                                               ushort_t* __restrict__ lo, int n) {
  int i = blockIdx.x * 256 + threadIdx.x;
  const int stride = gridDim.x * 256;
  for (; i < n; i += stride) {
    float v = src[i];
    uint32_t u = __float_as_uint(v);
    uint32_t rh = u + 0x7FFFu + ((u >> 16) & 1u);   // RNE to bf16
    ushort_t h = (ushort_t)(rh >> 16);
    float hf = __uint_as_float(((uint32_t)h) << 16);
    float l = v - hf;
    uint32_t ul = __float_as_uint(l);
    uint32_t rl = ul + 0x7FFFu + ((ul >> 16) & 1u);
    hi[i] = h;
    lo[i] = (ushort_t)(rl >> 16);
  }
}

// ---------------------------------------------------------------- softmax over t
__global__ __launch_bounds__(256) void k_softmax_t(
    const float* __restrict__ TA, float* __restrict__ attn) {
  __shared__ float redm[8][32];
  __shared__ float reds[8][32];
  const int ol = threadIdx.x & 31;
  const int tg = threadIdx.x >> 5;
  const int o = blockIdx.x * 32 + ol;
  float mx = -1e30f;
  for (int i = 0; i < 64; ++i) {
    float v = TA[(size_t)(tg * 64 + i) * OUT_DIM + o];
    mx = fmaxf(mx, v);
  }
  redm[tg][ol] = mx;
  __syncthreads();
  float m = redm[0][ol];
#pragma unroll
  for (int j = 1; j < 8; ++j) m = fmaxf(m, redm[j][ol]);
  float s = 0.f;
  for (int i = 0; i < 64; ++i) {
    float v = TA[(size_t)(tg * 64 + i) * OUT_DIM + o];
    s += __expf(v - m);
  }
  reds[tg][ol] = s;
  __syncthreads();
  float tot = 0.f;
#pragma unroll
  for (int j = 0; j < 8; ++j) tot += reds[j][ol];
  const float inv = 1.0f / tot;
  for (int i = 0; i < 64; ++i) {
    int t = tg * 64 + i;
    float v = TA[(size_t)t * OUT_DIM + o];
    attn[(size_t)t * OUT_DIM + o] = __expf(v - m) * inv;
  }
}

// ---------------------------------------------------------------- MFMA GEMM, 3-term split
__global__ __launch_bounds__(256) void k_gemm_split3(
    const ushort_t* __restrict__ Ahi, const ushort_t* __restrict__ Alo,
    const ushort_t* __restrict__ Bhi, const ushort_t* __restrict__ Blo,
    const float* __restrict__ bias, float* __restrict__ C,
    int M, int N, int K) {
  __shared__ ushort_t At[2][128 * 40];
  __shared__ ushort_t Bt[2][128 * 40];
  const int tid = threadIdx.x;
  const int row0 = blockIdx.x * 128, col0 = blockIdx.y * 128;
  const int w = tid >> 6, lane = tid & 63;
  const int wm = (w >> 1) * 64, wn = (w & 1) * 64;
  const int l15 = lane & 15, quad = lane >> 4;
  float4v acc[4][4];
#pragma unroll
  for (int i = 0; i < 4; ++i)
#pragma unroll
    for (int j = 0; j < 4; ++j) acc[i][j] = (float4v){0.f, 0.f, 0.f, 0.f};

  for (int k0 = 0; k0 < K; k0 += 32) {
#pragma unroll
    for (int it = 0; it < 2; ++it) {
      int idx = it * 256 + tid;          // 0..511
      int r = idx >> 2;                  // row 0..127
      int c8 = (idx & 3) << 3;           // k-offset {0,8,16,24}
      *(uint4*)(&At[0][r * 40 + c8]) =
          *(const uint4*)(&Ahi[(size_t)(row0 + r) * K + k0 + c8]);
      *(uint4*)(&At[1][r * 40 + c8]) =
          *(const uint4*)(&Alo[(size_t)(row0 + r) * K + k0 + c8]);
      *(uint4*)(&Bt[0][r * 40 + c8]) =
          *(const uint4*)(&Bhi[(size_t)(col0 + r) * K + k0 + c8]);
      *(uint4*)(&Bt[1][r * 40 + c8]) =
          *(const uint4*)(&Blo[(size_t)(col0 + r) * K + k0 + c8]);
    }
    __syncthreads();
    short8 ah[4], al[4], bh[4], bl[4];
    const int koff = quad * 8;
#pragma unroll
    for (int i = 0; i < 4; ++i) {
      ah[i] = *(const short8*)(&At[0][(wm + i * 16 + l15) * 40 + koff]);
      al[i] = *(const short8*)(&At[1][(wm + i * 16 + l15) * 40 + koff]);
      bh[i] = *(const short8*)(&Bt[0][(wn + i * 16 + l15) * 40 + koff]);
      bl[i] = *(const short8*)(&Bt[1][(wn + i * 16 + l15) * 40 + koff]);
    }
#pragma unroll
    for (int i = 0; i < 4; ++i)
#pragma unroll
      for (int j = 0; j < 4; ++j) {
        acc[i][j] = __builtin_amdgcn_mfma_f32_16x16x32_bf16(ah[i], bh[j], acc[i][j], 0, 0, 0);
        acc[i][j] = __builtin_amdgcn_mfma_f32_16x16x32_bf16(ah[i], bl[j], acc[i][j], 0, 0, 0);
        acc[i][j] = __builtin_amdgcn_mfma_f32_16x16x32_bf16(al[i], bh[j], acc[i][j], 0, 0, 0);
      }
    __syncthreads();
  }
#pragma unroll
  for (int j = 0; j < 4; ++j) {
    const int col = col0 + wn + j * 16 + l15;
    const float bv = bias ? bias[col] : 0.f;
#pragma unroll
    for (int i = 0; i < 4; ++i) {
#pragma unroll
      for (int r = 0; r < 4; ++r) {
        int row = row0 + wm + i * 16 + quad * 4 + r;
        C[(size_t)row * N + col] = acc[i][j][r] + bv;
      }
    }
  }
}

// ---------------------------------------------------------------- MFMA GEMM, spike-A 2-term
__global__ __launch_bounds__(256) void k_gemm_spike2(
    const float* __restrict__ A, const ushort_t* __restrict__ Bhi,
    const ushort_t* __restrict__ Blo, const float* __restrict__ bias,
    float* __restrict__ C, int M, int N, int K) {
  __shared__ ushort_t At[128 * 72];
  __shared__ ushort_t Bt[2][128 * 72];
  const int tid = threadIdx.x;
  const int row0 = blockIdx.x * 128, col0 = blockIdx.y * 128;
  const int w = tid >> 6, lane = tid & 63;
  const int wm = (w >> 1) * 64, wn = (w & 1) * 64;
  const int l15 = lane & 15, quad = lane >> 4;
  float4v acc[4][4];
#pragma unroll
  for (int i = 0; i < 4; ++i)
#pragma unroll
    for (int j = 0; j < 4; ++j) acc[i][j] = (float4v){0.f, 0.f, 0.f, 0.f};

  for (int k0 = 0; k0 < K; k0 += 64) {
#pragma unroll
    for (int it = 0; it < 4; ++it) {
      int idx = it * 256 + tid;          // 0..1023
      int r = idx >> 3;                  // row 0..127
      int c8 = (idx & 7) << 3;           // k-offset 0..56 step 8
      uint4 pa = *(const uint4*)(&A[(size_t)(row0 + r) * K + k0 + c8]);
      uint4 pb = *(const uint4*)(&A[(size_t)(row0 + r) * K + k0 + c8 + 4]);
      uint4 st;
      st.x = (pa.x >> 16) | (pa.y & 0xFFFF0000u);
      st.y = (pa.z >> 16) | (pa.w & 0xFFFF0000u);
      st.z = (pb.x >> 16) | (pb.y & 0xFFFF0000u);
      st.w = (pb.z >> 16) | (pb.w & 0xFFFF0000u);
      *(uint4*)(&At[r * 72 + c8]) = st;
      *(uint4*)(&Bt[0][r * 72 + c8]) =
          *(const uint4*)(&Bhi[(size_t)(col0 + r) * K + k0 + c8]);
      *(uint4*)(&Bt[1][r * 72 + c8]) =
          *(const uint4*)(&Blo[(size_t)(col0 + r) * K + k0 + c8]);
    }
    __syncthreads();
#pragma unroll
    for (int ks = 0; ks < 2; ++ks) {
      short8 a[4], bh[4], bl[4];
      const int koff = ks * 32 + quad * 8;
#pragma unroll
      for (int i = 0; i < 4; ++i) {
        a[i] = *(const short8*)(&At[(wm + i * 16 + l15) * 72 + koff]);
        bh[i] = *(const short8*)(&Bt[0][(wn + i * 16 + l15) * 72 + koff]);
        bl[i] = *(const short8*)(&Bt[1][(wn + i * 16 + l15) * 72 + koff]);
      }
#pragma unroll
      for (int i = 0; i < 4; ++i)
#pragma unroll
        for (int j = 0; j < 4; ++j) {
          acc[i][j] = __builtin_amdgcn_mfma_f32_16x16x32_bf16(a[i], bh[j], acc[i][j], 0, 0, 0);
          acc[i][j] = __builtin_amdgcn_mfma_f32_16x16x32_bf16(a[i], bl[j], acc[i][j], 0, 0, 0);
        }
    }
    __syncthreads();
  }
#pragma unroll
  for (int j = 0; j < 4; ++j) {
    const int col = col0 + wn + j * 16 + l15;
    const float bv = bias ? bias[col] : 0.f;
#pragma unroll
    for (int i = 0; i < 4; ++i) {
#pragma unroll
      for (int r = 0; r < 4; ++r) {
        int row = row0 + wm + i * 16 + quad * 4 + r;
        C[(size_t)row * N + col] = acc[i][j][r] + bv;
      }
    }
  }
}

// ---------------------------------------------------------------- LIF scan #1
__global__ __launch_bounds__(256) void k_lif1(float* __restrict__ p) {
  const int id = blockIdx.x * 256 + threadIdx.x;  // 0..32767
  const size_t base = (size_t)(id >> 9) * (T_STEPS * HID) + (id & 511);
  float mem = 0.f;
  for (int t0 = 0; t0 < T_STEPS; t0 += 8) {
    float v[8];
#pragma unroll
    for (int j = 0; j < 8; ++j) v[j] = p[base + (size_t)(t0 + j) * HID];
#pragma unroll
    for (int j = 0; j < 8; ++j) {
      float nm = BETA * mem + v[j];
      float sp = nm > THR ? 1.0f : 0.0f;
      p[base + (size_t)(t0 + j) * HID] = sp;
      mem = nm - sp;
    }
  }
}

// ---------------------------------------------------------------- recurrent scan (R7)
// Free-running waves, NO block barrier in the scan. Each wave polls all 512
// qword pairs of slot (t-1) itself (8 loads/lane, straggler-only retries),
// deposits into its wave-private LDS region, computes, in-wave swizzle-reduce.
// P slot layout: qword pairs (mem0,mem1) at [rr*2], rr = membrane row 0..511.
// Exchange semantics: agent-scope relaxed atomics (R5-proven).
__global__ __launch_bounds__(512) void k_recurrent_cp(
    const float* __restrict__ W, const float* __restrict__ b_hh,
    float* __restrict__ rp, float* __restrict__ P) {
  const int tid = threadIdx.x;
  const int grp = blockIdx.x & 31;  // stride-32 members: same XCD under %8 RR
  const int j   = blockIdx.x >> 5;  // output-column block 0..7
  const int w   = tid >> 6;         // wave 0..7
  const int l   = tid & 63;
  const int q   = l >> 3;           // row-in-group 0..7
  const int c   = l & 7;            // k-chunk of this lane
  const int row = (w << 3) + q;     // 0..63 output row within block
  const int g0  = j << 6;

  __shared__ float memLDS[8][2][8 * 72];  // [wave][ob][chunk*72 + k] private
  float* wl0 = &memLDS[w][0][0];
  float* wl1 = &memLDS[w][1][0];

  // zero-init own wave region only (wave-private; no barrier needed)
  for (int i = l; i < 2 * 8 * 72; i += 64) ((float*)memLDS[w])[i] = 0.f;

  float Wreg[64];
  {
    const float* wrow = W + (size_t)(g0 + row) * HID + (c << 6);
#pragma unroll
    for (int k4 = 0; k4 < 16; ++k4) {
      float4 w4 = *(const float4*)(wrow + 4 * k4);
      Wreg[4 * k4 + 0] = w4.x; Wreg[4 * k4 + 1] = w4.y;
      Wreg[4 * k4 + 2] = w4.z; Wreg[4 * k4 + 3] = w4.w;
    }
  }

  const bool lif = (c == 0);
  const int og = g0 + row;
  const size_t rp_b0 = (size_t)(grp * 2 + 0) * (T_STEPS * HID) + og;
  const size_t rp_b1 = (size_t)(grp * 2 + 1) * (T_STEPS * HID) + og;
  const float bhh_v = lif ? b_hh[og] : 0.f;
  float mem0 = 0.f, mem1 = 0.f;

  const uint64_t* P64 = (const uint64_t*)P;
  uint64_t* P64w = (uint64_t*)P;

  for (int t = 0; t < T_STEPS; ++t) {
    float ip0 = 0.f, ip1 = 0.f;
    if (lif) {
      ip0 = rp[rp_b0 + (size_t)t * HID];
      ip1 = rp[rp_b1 + (size_t)t * HID];
    }
    if (t > 0) {
      // slot of step t-1, qword-pair base
      const uint64_t* base = P64 + ((size_t)(t - 1) * 32 + grp) * 512;
      uint64_t u[8];
#pragma unroll
      for (int i = 0; i < 8; ++i)
        u[i] = __hip_atomic_load(base + (i << 6) + l, __ATOMIC_RELAXED,
                                 __HIP_MEMORY_SCOPE_AGENT);
      int tries = 0;
      for (;;) {
        bool any = false;
#pragma unroll
        for (int i = 0; i < 8; ++i) {
          any = any || ((uint32_t)u[i] == SENT) || ((uint32_t)(u[i] >> 32) == SENT);
        }
        if (!any) break;
        if (++tries > 16) __builtin_amdgcn_s_sleep(1);
#pragma unroll
        for (int i = 0; i < 8; ++i) {
          if (((uint32_t)u[i] == SENT) || ((uint32_t)(u[i] >> 32) == SENT))
            u[i] = __hip_atomic_load(base + (i << 6) + l, __ATOMIC_RELAXED,
                                     __HIP_MEMORY_SCOPE_AGENT);
        }
      }
#pragma unroll
      for (int i = 0; i < 8; ++i) {
        wl0[i * 72 + l] = __uint_as_float((uint32_t)u[i]);
        wl1[i * 72 + l] = __uint_as_float((uint32_t)(u[i] >> 32));
      }
    }
    // wave-local: compiler inserts lgkmcnt between ds_write and ds_read

    float p0a = 0.f, p0b = 0.f, p1a = 0.f, p1b = 0.f;
    {
      const float4* m0 = (const float4*)&wl0[c * 72];
      const float4* m1 = (const float4*)&wl1[c * 72];
#pragma unroll
      for (int k4 = 0; k4 < 16; ++k4) {
        float4 a = m0[k4];
        float4 b = m1[k4];
        p0a = fmaf(Wreg[4 * k4 + 0], a.x, p0a);
        p0b = fmaf(Wreg[4 * k4 + 1], a.y, p0b);
        p0a = fmaf(Wreg[4 * k4 + 2], a.z, p0a);
        p0b = fmaf(Wreg[4 * k4 + 3], a.w, p0b);
        p1a = fmaf(Wreg[4 * k4 + 0], b.x, p1a);
        p1b = fmaf(Wreg[4 * k4 + 1], b.y, p1b);
        p1a = fmaf(Wreg[4 * k4 + 2], b.z, p1a);
        p1b = fmaf(Wreg[4 * k4 + 3], b.w, p1b);
      }
    }
    const int i0 = __float_as_int(p0a + p0b);
    const int i1 = __float_as_int(p1a + p1b);
    // serial ascending-chunk reduce across lanes (l&56)+ss  (== old scratch)
    float s0 = 0.f, s1 = 0.f;
#define RED(ss)                                                                 \
    s0 += __int_as_float(__builtin_amdgcn_ds_swizzle(i0, ((ss) << 5) | 0x18)); \
    s1 += __int_as_float(__builtin_amdgcn_ds_swizzle(i1, ((ss) << 5) | 0x18));
    RED(0) RED(1) RED(2) RED(3) RED(4) RED(5) RED(6) RED(7)
#undef RED

    if (lif) {
      const float nm0 = BETA * mem0 + ip0 + s0 + bhh_v;
      const float sp0 = nm0 > THR ? 1.0f : 0.0f;
      mem0 = nm0 - sp0;
      const float nm1 = BETA * mem1 + ip1 + s1 + bhh_v;
      const float sp1 = nm1 > THR ? 1.0f : 0.0f;
      mem1 = nm1 - sp1;
      const uint64_t pk =
          ((uint64_t)__float_as_uint(mem1) << 32) | (uint64_t)__float_as_uint(mem0);
      __hip_atomic_store(P64w + ((size_t)t * 32 + grp) * 512 + og, pk,
                         __ATOMIC_RELAXED, __HIP_MEMORY_SCOPE_AGENT);
      rp[rp_b0 + (size_t)t * HID] = sp0;
      rp[rp_b1 + (size_t)t * HID] = sp1;
    }
  }
}

// ---------------------------------------------------------------- attend + threshold
__global__ __launch_bounds__(256) void k_attend(
    const float* __restrict__ op, const float* __restrict__ attn,
    const float* __restrict__ b_out, float* __restrict__ out) {
  const int b = blockIdx.x;
  const int o = threadIdx.x;
  float s = b_out[o];
  const float* opb = op + (size_t)b * T_STEPS * OUT_DIM + o;
  for (int t0 = 0; t0 < T_STEPS; t0 += 8) {
    float av[8], pv[8];
#pragma unroll
    for (int j = 0; j < 8; ++j) {
      av[j] = attn[(size_t)(t0 + j) * OUT_DIM + o];
      pv[j] = opb[(size_t)(t0 + j) * OUT_DIM];
    }
#pragma unroll
    for (int j = 0; j < 8; ++j) s = fmaf(av[j], pv[j], s);
  }
  out[b * OUT_DIM + o] = s > THR ? 1.0f : 0.0f;
}

// ---------------------------------------------------------------- launch
extern "C" void kernel_launch(void* const* d_in, const int* in_sizes, int n_in,
                              void* d_out, int out_size, void* d_ws, size_t ws_size,
                              hipStream_t stream) {
  (void)in_sizes; (void)n_in; (void)out_size; (void)ws_size;
  const float* x     = (const float*)d_in[0];
  const float* W_in  = (const float*)d_in[1];
  const float* b_in  = (const float*)d_in[2];
  const float* W_ih  = (const float*)d_in[3];
  const float* b_ih  = (const float*)d_in[4];
  const float* W_hh  = (const float*)d_in[5];
  const float* b_hh  = (const float*)d_in[6];
  const float* W_out = (const float*)d_in[7];
  const float* b_out = (const float*)d_in[8];
  const float* TA    = (const float*)d_in[9];

  float* ws = (float*)d_ws;
  float* proj  = ws;                           // 16.78M floats: GEMM1 out / P / out_proj
  float* rproj = proj + (size_t)32768 * 512;   // 16.78M floats: x-splits, then GEMM2 out
  float* attn  = rproj + (size_t)32768 * 512;  // 131072 floats
  ushort_t* wih_hi = (ushort_t*)(attn + 512 * 256);
  ushort_t* wih_lo = wih_hi + 512 * 512;
  ushort_t* win_hi = wih_lo + 512 * 512;
  ushort_t* win_lo = win_hi + 512 * 256;
  ushort_t* wout_hi = win_lo + 512 * 256;
  ushort_t* wout_lo = wout_hi + 256 * 512;
  ushort_t* x_hi = (ushort_t*)rproj;
  ushort_t* x_lo = x_hi + (size_t)32768 * 256;
  float* P = proj;            // exchange slots [t][grp][rr][2] qword pairs
  float* out_proj = proj;     // (b*T, O) fp32, written after recurrent

  k_softmax_t<<<8, 256, 0, stream>>>(TA, attn);
  k_split<<<4096, 256, 0, stream>>>(x, x_hi, x_lo, 32768 * 256);
  k_split<<<512, 256, 0, stream>>>(W_in, win_hi, win_lo, 512 * 256);
  k_split<<<512, 256, 0, stream>>>(W_ih, wih_hi, wih_lo, 512 * 512);
  k_split<<<512, 256, 0, stream>>>(W_out, wout_hi, wout_lo, 256 * 512);

  // GEMM1: proj = x @ W_in^T + b_in   (M=32768, N=512, K=256)
  k_gemm_split3<<<dim3(256, 4), 256, 0, stream>>>(
      x_hi, x_lo, win_hi, win_lo, b_in, proj, 32768, 512, 256);
  k_lif1<<<128, 256, 0, stream>>>(proj);
  // GEMM2: rproj = spikes @ W_ih^T + b_ih   (M=32768, N=512, K=512)
  k_gemm_spike2<<<dim3(256, 4), 256, 0, stream>>>(
      proj, wih_hi, wih_lo, b_ih, rproj, 32768, 512, 512);
  k_fill_nan<<<256, 256, 0, stream>>>((uint32_t*)P);  // proj dead after GEMM2
  k_recurrent_cp<<<256, 512, 0, stream>>>(W_hh, b_hh, rproj, P);
  // GEMM3: out_proj = tspikes @ W_out^T   (M=32768, N=256, K=512, no bias)
  k_gemm_spike2<<<dim3(256, 2), 256, 0, stream>>>(
      rproj, wout_hi, wout_lo, nullptr, out_proj, 32768, 256, 512);
  k_attend<<<64, 256, 0, stream>>>(out_proj, attn, b_out, (float*)d_out);
}

// Round 4
// 1336.253 us; speedup vs baseline: 20.8062x; 1.3305x over previous
//
#include <hip/hip_runtime.h>
#include <hip/hip_bf16.h>
#include <cstdint>

// PhaseEncodingSNN: B=64, T=512, I=256, H=512, O=256.
// R8: k_recurrent_cp exchange -> DUAL-RAIL:
//  FAST rail: 4-slot ring (1MB, fits per-XCD L2) of 16B entries
//    {mem0, mem1, tag=t, t^mem0^mem1}, sc0 store/load. Consumer accepts ONLY
//    on tag+checksum match -> stale-L1 / write-back-stuck / ring-reuse / torn
//    reads all REJECT (rail can be slow or silent, never wrong).
//  SLOW rail: 8-slot ring of SENT-sentinel qwords, R5-proven agent-scope
//    relaxed atomics. Poison-3-ahead reuse (poison@t kills value@t-5, whose
//    readers finished since all blocks >= t-1; __syncthreads' vmcnt(0) drains
//    stores each step so poison is visible before any later-step store).
//  Poll round: fast dwordx4 issued first, slow qword second, vmcnt(1) waits
//  fast only (~250cy L2 round); slow checked on fast-miss. No escalation
//  counter -> no R6-style burn; worst case == R5 + eps; no hang possible.
//  Rings alias proj (P array gone): ws shrinks, 64MB NaN-fill -> 2MB init.
//  All FMA order / swizzle reduce / LIF arithmetic bitwise == R5.
// GEMMs / LIF1 / softmax / attend unchanged.

#define T_STEPS 512
#define BATCH 64
#define HID 512
#define IN_DIM 256
#define OUT_DIM 256
#define BETA 0.9f
#define THR 1.0f
#define SENT 0x7FC00000u
#define RF 4   // fast ring slots
#define RS 8   // slow ring slots

typedef __attribute__((ext_vector_type(8))) short short8;
typedef __attribute__((ext_vector_type(4))) float float4v;
typedef __attribute__((ext_vector_type(4))) unsigned int uint32x4;
typedef unsigned short ushort_t;

// ---------------------------------------------------------------- ring init
// fast ring: 4*32*512 = 65536 entries (16B, tag=0xFFFFFFFF never matches t).
// slow ring: 8*32*512 = 131072 qwords = SENT|SENT.
__global__ __launch_bounds__(256) void k_init_rings(uint32x4* __restrict__ FR,
                                                    uint64_t* __restrict__ SR) {
  const int idx = blockIdx.x * 256 + threadIdx.x;  // 65536 threads
  FR[idx] = (uint32x4){0u, 0u, 0xFFFFFFFFu, 0u};
  const uint64_t SP = ((uint64_t)SENT << 32) | (uint64_t)SENT;
  SR[idx] = SP;
  SR[idx + 65536] = SP;
}

// ---------------------------------------------------------------- fp32 -> hi/lo bf16 split
__global__ __launch_bounds__(256) void k_split(const float* __restrict__ src,
                                               ushort_t* __restrict__ hi,
                                               ushort_t* __restrict__ lo, int n) {
  int i = blockIdx.x * 256 + threadIdx.x;
  const int stride = gridDim.x * 256;
  for (; i < n; i += stride) {
    float v = src[i];
    uint32_t u = __float_as_uint(v);
    uint32_t rh = u + 0x7FFFu + ((u >> 16) & 1u);   // RNE to bf16
    ushort_t h = (ushort_t)(rh >> 16);
    float hf = __uint_as_float(((uint32_t)h) << 16);
    float l = v - hf;
    uint32_t ul = __float_as_uint(l);
    uint32_t rl = ul + 0x7FFFu + ((ul >> 16) & 1u);
    hi[i] = h;
    lo[i] = (ushort_t)(rl >> 16);
  }
}

// ---------------------------------------------------------------- softmax over t
__global__ __launch_bounds__(256) void k_softmax_t(
    const float* __restrict__ TA, float* __restrict__ attn) {
  __shared__ float redm[8][32];
  __shared__ float reds[8][32];
  const int ol = threadIdx.x & 31;
  const int tg = threadIdx.x >> 5;
  const int o = blockIdx.x * 32 + ol;
  float mx = -1e30f;
  for (int i = 0; i < 64; ++i) {
    float v = TA[(size_t)(tg * 64 + i) * OUT_DIM + o];
    mx = fmaxf(mx, v);
  }
  redm[tg][ol] = mx;
  __syncthreads();
  float m = redm[0][ol];
#pragma unroll
  for (int j = 1; j < 8; ++j) m = fmaxf(m, redm[j][ol]);
  float s = 0.f;
  for (int i = 0; i < 64; ++i) {
    float v = TA[(size_t)(tg * 64 + i) * OUT_DIM + o];
    s += __expf(v - m);
  }
  reds[tg][ol] = s;
  __syncthreads();
  float tot = 0.f;
#pragma unroll
  for (int j = 0; j < 8; ++j) tot += reds[j][ol];
  const float inv = 1.0f / tot;
  for (int i = 0; i < 64; ++i) {
    int t = tg * 64 + i;
    float v = TA[(size_t)t * OUT_DIM + o];
    attn[(size_t)t * OUT_DIM + o] = __expf(v - m) * inv;
  }
}

// ---------------------------------------------------------------- MFMA GEMM, 3-term split
__global__ __launch_bounds__(256) void k_gemm_split3(
    const ushort_t* __restrict__ Ahi, const ushort_t* __restrict__ Alo,
    const ushort_t* __restrict__ Bhi, const ushort_t* __restrict__ Blo,
    const float* __restrict__ bias, float* __restrict__ C,
    int M, int N, int K) {
  __shared__ ushort_t At[2][128 * 40];
  __shared__ ushort_t Bt[2][128 * 40];
  const int tid = threadIdx.x;
  const int row0 = blockIdx.x * 128, col0 = blockIdx.y * 128;
  const int w = tid >> 6, lane = tid & 63;
  const int wm = (w >> 1) * 64, wn = (w & 1) * 64;
  const int l15 = lane & 15, quad = lane >> 4;
  float4v acc[4][4];
#pragma unroll
  for (int i = 0; i < 4; ++i)
#pragma unroll
    for (int j = 0; j < 4; ++j) acc[i][j] = (float4v){0.f, 0.f, 0.f, 0.f};

  for (int k0 = 0; k0 < K; k0 += 32) {
#pragma unroll
    for (int it = 0; it < 2; ++it) {
      int idx = it * 256 + tid;          // 0..511
      int r = idx >> 2;                  // row 0..127
      int c8 = (idx & 3) << 3;           // k-offset {0,8,16,24}
      *(uint4*)(&At[0][r * 40 + c8]) =
          *(const uint4*)(&Ahi[(size_t)(row0 + r) * K + k0 + c8]);
      *(uint4*)(&At[1][r * 40 + c8]) =
          *(const uint4*)(&Alo[(size_t)(row0 + r) * K + k0 + c8]);
      *(uint4*)(&Bt[0][r * 40 + c8]) =
          *(const uint4*)(&Bhi[(size_t)(col0 + r) * K + k0 + c8]);
      *(uint4*)(&Bt[1][r * 40 + c8]) =
          *(const uint4*)(&Blo[(size_t)(col0 + r) * K + k0 + c8]);
    }
    __syncthreads();
    short8 ah[4], al[4], bh[4], bl[4];
    const int koff = quad * 8;
#pragma unroll
    for (int i = 0; i < 4; ++i) {
      ah[i] = *(const short8*)(&At[0][(wm + i * 16 + l15) * 40 + koff]);
      al[i] = *(const short8*)(&At[1][(wm + i * 16 + l15) * 40 + koff]);
      bh[i] = *(const short8*)(&Bt[0][(wn + i * 16 + l15) * 40 + koff]);
      bl[i] = *(const short8*)(&Bt[1][(wn + i * 16 + l15) * 40 + koff]);
    }
#pragma unroll
    for (int i = 0; i < 4; ++i)
#pragma unroll
      for (int j = 0; j < 4; ++j) {
        acc[i][j] = __builtin_amdgcn_mfma_f32_16x16x32_bf16(ah[i], bh[j], acc[i][j], 0, 0, 0);
        acc[i][j] = __builtin_amdgcn_mfma_f32_16x16x32_bf16(ah[i], bl[j], acc[i][j], 0, 0, 0);
        acc[i][j] = __builtin_amdgcn_mfma_f32_16x16x32_bf16(al[i], bh[j], acc[i][j], 0, 0, 0);
      }
    __syncthreads();
  }
#pragma unroll
  for (int j = 0; j < 4; ++j) {
    const int col = col0 + wn + j * 16 + l15;
    const float bv = bias ? bias[col] : 0.f;
#pragma unroll
    for (int i = 0; i < 4; ++i) {
#pragma unroll
      for (int r = 0; r < 4; ++r) {
        int row = row0 + wm + i * 16 + quad * 4 + r;
        C[(size_t)row * N + col] = acc[i][j][r] + bv;
      }
    }
  }
}

// ---------------------------------------------------------------- MFMA GEMM, spike-A 2-term
__global__ __launch_bounds__(256) void k_gemm_spike2(
    const float* __restrict__ A, const ushort_t* __restrict__ Bhi,
    const ushort_t* __restrict__ Blo, const float* __restrict__ bias,
    float* __restrict__ C, int M, int N, int K) {
  __shared__ ushort_t At[128 * 72];
  __shared__ ushort_t Bt[2][128 * 72];
  const int tid = threadIdx.x;
  const int row0 = blockIdx.x * 128, col0 = blockIdx.y * 128;
  const int w = tid >> 6, lane = tid & 63;
  const int wm = (w >> 1) * 64, wn = (w & 1) * 64;
  const int l15 = lane & 15, quad = lane >> 4;
  float4v acc[4][4];
#pragma unroll
  for (int i = 0; i < 4; ++i)
#pragma unroll
    for (int j = 0; j < 4; ++j) acc[i][j] = (float4v){0.f, 0.f, 0.f, 0.f};

  for (int k0 = 0; k0 < K; k0 += 64) {
#pragma unroll
    for (int it = 0; it < 4; ++it) {
      int idx = it * 256 + tid;          // 0..1023
      int r = idx >> 3;                  // row 0..127
      int c8 = (idx & 7) << 3;           // k-offset 0..56 step 8
      uint4 pa = *(const uint4*)(&A[(size_t)(row0 + r) * K + k0 + c8]);
      uint4 pb = *(const uint4*)(&A[(size_t)(row0 + r) * K + k0 + c8 + 4]);
      uint4 st;
      st.x = (pa.x >> 16) | (pa.y & 0xFFFF0000u);
      st.y = (pa.z >> 16) | (pa.w & 0xFFFF0000u);
      st.z = (pb.x >> 16) | (pb.y & 0xFFFF0000u);
      st.w = (pb.z >> 16) | (pb.w & 0xFFFF0000u);
      *(uint4*)(&At[r * 72 + c8]) = st;
      *(uint4*)(&Bt[0][r * 72 + c8]) =
          *(const uint4*)(&Bhi[(size_t)(col0 + r) * K + k0 + c8]);
      *(uint4*)(&Bt[1][r * 72 + c8]) =
          *(const uint4*)(&Blo[(size_t)(col0 + r) * K + k0 + c8]);
    }
    __syncthreads();
#pragma unroll
    for (int ks = 0; ks < 2; ++ks) {
      short8 a[4], bh[4], bl[4];
      const int koff = ks * 32 + quad * 8;
#pragma unroll
      for (int i = 0; i < 4; ++i) {
        a[i] = *(const short8*)(&At[(wm + i * 16 + l15) * 72 + koff]);
        bh[i] = *(const short8*)(&Bt[0][(wn + i * 16 + l15) * 72 + koff]);
        bl[i] = *(const short8*)(&Bt[1][(wn + i * 16 + l15) * 72 + koff]);
      }
#pragma unroll
      for (int i = 0; i < 4; ++i)
#pragma unroll
        for (int j = 0; j < 4; ++j) {
          acc[i][j] = __builtin_amdgcn_mfma_f32_16x16x32_bf16(a[i], bh[j], acc[i][j], 0, 0, 0);
          acc[i][j] = __builtin_amdgcn_mfma_f32_16x16x32_bf16(a[i], bl[j], acc[i][j], 0, 0, 0);
        }
    }
    __syncthreads();
  }
#pragma unroll
  for (int j = 0; j < 4; ++j) {
    const int col = col0 + wn + j * 16 + l15;
    const float bv = bias ? bias[col] : 0.f;
#pragma unroll
    for (int i = 0; i < 4; ++i) {
#pragma unroll
      for (int r = 0; r < 4; ++r) {
        int row = row0 + wm + i * 16 + quad * 4 + r;
        C[(size_t)row * N + col] = acc[i][j][r] + bv;
      }
    }
  }
}

// ---------------------------------------------------------------- LIF scan #1
__global__ __launch_bounds__(256) void k_lif1(float* __restrict__ p) {
  const int id = blockIdx.x * 256 + threadIdx.x;  // 0..32767
  const size_t base = (size_t)(id >> 9) * (T_STEPS * HID) + (id & 511);
  float mem = 0.f;
  for (int t0 = 0; t0 < T_STEPS; t0 += 8) {
    float v[8];
#pragma unroll
    for (int j = 0; j < 8; ++j) v[j] = p[base + (size_t)(t0 + j) * HID];
#pragma unroll
    for (int j = 0; j < 8; ++j) {
      float nm = BETA * mem + v[j];
      float sp = nm > THR ? 1.0f : 0.0f;
      p[base + (size_t)(t0 + j) * HID] = sp;
      mem = nm - sp;
    }
  }
}

// ---------------------------------------------------------------- recurrent scan (R8)
// R5 structure (transposed mapping, 1 barrier/step, parity dbuf memLDS,
// in-wave swizzle reduce) + dual-rail exchange (see header).
__global__ __launch_bounds__(512) void k_recurrent_cp(
    const float* __restrict__ W, const float* __restrict__ b_hh,
    float* __restrict__ rp, uint32x4* __restrict__ FR,
    uint64_t* __restrict__ SR) {
  const int tid = threadIdx.x;
  const int grp = blockIdx.x & 31;  // stride-32 members: same XCD under %8 RR
  const int j   = blockIdx.x >> 5;  // output-column block 0..7
  const int w   = tid >> 6;         // wave 0..7
  const int l   = tid & 63;
  const int q   = l >> 3;           // row-in-group 0..7
  const int c   = l & 7;            // k-chunk of this lane
  const int row = (w << 3) + q;     // 0..63 output row within block
  const int g0  = j << 6;

  __shared__ float memLDS[2][2][8 * 72];  // [parity][ob][chunk*72 + k]

  for (int i = tid; i < 2 * 2 * 8 * 72; i += 512) ((float*)memLDS)[i] = 0.f;

  float Wreg[64];
  {
    const float* wrow = W + (size_t)(g0 + row) * HID + (c << 6);
#pragma unroll
    for (int k4 = 0; k4 < 16; ++k4) {
      float4 w4 = *(const float4*)(wrow + 4 * k4);
      Wreg[4 * k4 + 0] = w4.x; Wreg[4 * k4 + 1] = w4.y;
      Wreg[4 * k4 + 2] = w4.z; Wreg[4 * k4 + 3] = w4.w;
    }
  }

  const bool lif = (c == 0);
  const int og = g0 + row;
  const size_t rp_b0 = (size_t)(grp * 2 + 0) * (T_STEPS * HID) + og;
  const size_t rp_b1 = (size_t)(grp * 2 + 1) * (T_STEPS * HID) + og;
  const float bhh_v = lif ? b_hh[og] : 0.f;
  float mem0 = 0.f, mem1 = 0.f;

  const int rg = (tid < g0) ? tid : tid + 64;        // remote row (tid<448)
  const int raddr = (rg >> 6) * 72 + (rg & 63);
  const uint64_t SENTP = ((uint64_t)SENT << 32) | (uint64_t)SENT;

  __syncthreads();

  for (int t = 0; t < T_STEPS; ++t) {
    const int par = t & 1;
    float ip0 = 0.f, ip1 = 0.f;
    if (lif) {
      ip0 = rp[rp_b0 + (size_t)t * HID];
      ip1 = rp[rp_b1 + (size_t)t * HID];
    }
    if (t > 0 && tid < 448) {
      const uint32_t want = (uint32_t)(t - 1);
      const uint32x4* fp_ = FR + (((size_t)((t - 1) & (RF - 1))) * 32 + grp) * 512 + rg;
      const uint64_t* sp_ = SR + (((size_t)((t - 1) & (RS - 1))) * 32 + grp) * 512 + rg;
      uint32_t r0, r1;
      int tries = 0;
      for (;;) {
        uint32x4 fq;
        // fast load FIRST (oldest outstanding -> vmcnt(1) isolates it)
        asm volatile("global_load_dwordx4 %0, %1, off sc0"
                     : "=v"(fq) : "v"(fp_) : "memory");
        uint64_t sq = __hip_atomic_load(sp_, __ATOMIC_RELAXED,
                                        __HIP_MEMORY_SCOPE_AGENT);
        // wait fast only; "+v"(fq) redefines fq so no use can hoist above
        asm volatile("s_waitcnt vmcnt(1)" : "+v"(fq) :: "memory");
        if (fq.z == want && fq.w == (want ^ fq.x ^ fq.y)) {
          r0 = fq.x; r1 = fq.y; break;          // fast rail hit (validated)
        }
        const uint32_t s0 = (uint32_t)sq, s1 = (uint32_t)(sq >> 32);
        if (s0 != SENT && s1 != SENT) { r0 = s0; r1 = s1; break; }  // slow hit
        if (++tries > 48) __builtin_amdgcn_s_sleep(1);
      }
      memLDS[par][0][raddr] = __uint_as_float(r0);
      memLDS[par][1][raddr] = __uint_as_float(r1);
    }
    __syncthreads();   // vmcnt(0)+lgkmcnt(0): ALSO the store-drain fence the
                       // slow-ring poison proof relies on. Do not weaken.

    float p0a = 0.f, p0b = 0.f, p1a = 0.f, p1b = 0.f;
    {
      const float4* m0 = (const float4*)&memLDS[par][0][c * 72];
      const float4* m1 = (const float4*)&memLDS[par][1][c * 72];
#pragma unroll
      for (int k4 = 0; k4 < 16; ++k4) {
        float4 a = m0[k4];
        float4 b = m1[k4];
        p0a = fmaf(Wreg[4 * k4 + 0], a.x, p0a);
        p0b = fmaf(Wreg[4 * k4 + 1], a.y, p0b);
        p0a = fmaf(Wreg[4 * k4 + 2], a.z, p0a);
        p0b = fmaf(Wreg[4 * k4 + 3], a.w, p0b);
        p1a = fmaf(Wreg[4 * k4 + 0], b.x, p1a);
        p1b = fmaf(Wreg[4 * k4 + 1], b.y, p1b);
        p1a = fmaf(Wreg[4 * k4 + 2], b.z, p1a);
        p1b = fmaf(Wreg[4 * k4 + 3], b.w, p1b);
      }
    }
    const int i0 = __float_as_int(p0a + p0b);
    const int i1 = __float_as_int(p1a + p1b);
    // serial ascending-chunk reduce across lanes (l&56)+ss  (== old scratch)
    float s0 = 0.f, s1 = 0.f;
#define RED(ss)                                                                 \
    s0 += __int_as_float(__builtin_amdgcn_ds_swizzle(i0, ((ss) << 5) | 0x18)); \
    s1 += __int_as_float(__builtin_amdgcn_ds_swizzle(i1, ((ss) << 5) | 0x18));
    RED(0) RED(1) RED(2) RED(3) RED(4) RED(5) RED(6) RED(7)
#undef RED

    if (lif) {
      const int npar = par ^ 1;
      const float nm0 = BETA * mem0 + ip0 + s0 + bhh_v;
      const float sp0 = nm0 > THR ? 1.0f : 0.0f;
      mem0 = nm0 - sp0;
      const float nm1 = BETA * mem1 + ip1 + s1 + bhh_v;
      const float sp1 = nm1 > THR ? 1.0f : 0.0f;
      mem1 = nm1 - sp1;
      const uint32_t w0 = __float_as_uint(mem0);
      const uint32_t w1 = __float_as_uint(mem1);
      // fast rail store (tag+checksum entry)
      uint32x4 e;
      e.x = w0; e.y = w1; e.z = (uint32_t)t; e.w = (uint32_t)t ^ w0 ^ w1;
      uint32x4* fo = FR + (((size_t)(t & (RF - 1))) * 32 + grp) * 512 + og;
      asm volatile("global_store_dwordx4 %0, %1, off sc0"
                   :: "v"(fo), "v"(e) : "memory");
      // slow rail store + poison (+3 ahead)
      const uint64_t pk = ((uint64_t)w1 << 32) | (uint64_t)w0;
      __hip_atomic_store(SR + (((size_t)(t & (RS - 1))) * 32 + grp) * 512 + og,
                         pk, __ATOMIC_RELAXED, __HIP_MEMORY_SCOPE_AGENT);
      __hip_atomic_store(SR + (((size_t)((t + 3) & (RS - 1))) * 32 + grp) * 512 + og,
                         SENTP, __ATOMIC_RELAXED, __HIP_MEMORY_SCOPE_AGENT);
      rp[rp_b0 + (size_t)t * HID] = sp0;
      rp[rp_b1 + (size_t)t * HID] = sp1;
      memLDS[npar][0][j * 72 + row] = mem0;
      memLDS[npar][1][j * 72 + row] = mem1;
    }
  }
}

// ---------------------------------------------------------------- attend + threshold
__global__ __launch_bounds__(256) void k_attend(
    const float* __restrict__ op, const float* __restrict__ attn,
    const float* __restrict__ b_out, float* __restrict__ out) {
  const int b = blockIdx.x;
  const int o = threadIdx.x;
  float s = b_out[o];
  const float* opb = op + (size_t)b * T_STEPS * OUT_DIM + o;
  for (int t0 = 0; t0 < T_STEPS; t0 += 8) {
    float av[8], pv[8];
#pragma unroll
    for (int j = 0; j < 8; ++j) {
      av[j] = attn[(size_t)(t0 + j) * OUT_DIM + o];
      pv[j] = opb[(size_t)(t0 + j) * OUT_DIM];
    }
#pragma unroll
    for (int j = 0; j < 8; ++j) s = fmaf(av[j], pv[j], s);
  }
  out[b * OUT_DIM + o] = s > THR ? 1.0f : 0.0f;
}

// ---------------------------------------------------------------- launch
extern "C" void kernel_launch(void* const* d_in, const int* in_sizes, int n_in,
                              void* d_out, int out_size, void* d_ws, size_t ws_size,
                              hipStream_t stream) {
  (void)in_sizes; (void)n_in; (void)out_size; (void)ws_size;
  const float* x     = (const float*)d_in[0];
  const float* W_in  = (const float*)d_in[1];
  const float* b_in  = (const float*)d_in[2];
  const float* W_ih  = (const float*)d_in[3];
  const float* b_ih  = (const float*)d_in[4];
  const float* W_hh  = (const float*)d_in[5];
  const float* b_hh  = (const float*)d_in[6];
  const float* W_out = (const float*)d_in[7];
  const float* b_out = (const float*)d_in[8];
  const float* TA    = (const float*)d_in[9];

  float* ws = (float*)d_ws;
  float* proj  = ws;                           // 16.78M floats: GEMM1 out / rings / out_proj
  float* rproj = proj + (size_t)32768 * 512;   // 16.78M floats: x-splits, then GEMM2 out
  float* attn  = rproj + (size_t)32768 * 512;  // 131072 floats
  ushort_t* wih_hi = (ushort_t*)(attn + 512 * 256);
  ushort_t* wih_lo = wih_hi + 512 * 512;
  ushort_t* win_hi = wih_lo + 512 * 512;
  ushort_t* win_lo = win_hi + 512 * 256;
  ushort_t* wout_hi = win_lo + 512 * 256;
  ushort_t* wout_lo = wout_hi + 256 * 512;
  ushort_t* x_hi = (ushort_t*)rproj;
  ushort_t* x_lo = x_hi + (size_t)32768 * 256;
  // exchange rings alias proj (dead between GEMM2 and GEMM3):
  uint32x4* FR = (uint32x4*)proj;                       // 1 MB fast ring
  uint64_t* SR = (uint64_t*)(proj + (size_t)262144);    // 1 MB slow ring @ +1MB
  float* out_proj = proj;     // (b*T, O) fp32, written after recurrent

  k_softmax_t<<<8, 256, 0, stream>>>(TA, attn);
  k_split<<<4096, 256, 0, stream>>>(x, x_hi, x_lo, 32768 * 256);
  k_split<<<512, 256, 0, stream>>>(W_in, win_hi, win_lo, 512 * 256);
  k_split<<<512, 256, 0, stream>>>(W_ih, wih_hi, wih_lo, 512 * 512);
  k_split<<<512, 256, 0, stream>>>(W_out, wout_hi, wout_lo, 256 * 512);

  // GEMM1: proj = x @ W_in^T + b_in   (M=32768, N=512, K=256)
  k_gemm_split3<<<dim3(256, 4), 256, 0, stream>>>(
      x_hi, x_lo, win_hi, win_lo, b_in, proj, 32768, 512, 256);
  k_lif1<<<128, 256, 0, stream>>>(proj);
  // GEMM2: rproj = spikes @ W_ih^T + b_ih   (M=32768, N=512, K=512)
  k_gemm_spike2<<<dim3(256, 4), 256, 0, stream>>>(
      proj, wih_hi, wih_lo, b_ih, rproj, 32768, 512, 512);
  k_init_rings<<<256, 256, 0, stream>>>(FR, SR);  // proj dead after GEMM2
  k_recurrent_cp<<<256, 512, 0, stream>>>(W_hh, b_hh, rproj, FR, SR);
  // GEMM3: out_proj = tspikes @ W_out^T   (M=32768, N=256, K=512, no bias)
  k_gemm_spike2<<<dim3(256, 2), 256, 0, stream>>>(
      rproj, wout_hi, wout_lo, nullptr, out_proj, 32768, 256, 512);
  k_attend<<<64, 256, 0, stream>>>(out_proj, attn, b_out, (float*)d_out);
}

// Round 6
// 990.107 us; speedup vs baseline: 28.0801x; 1.3496x over previous
//
#include <hip/hip_runtime.h>
#include <hip/hip_bf16.h>
#include <cstdint>

// PhaseEncodingSNN: B=64, T=512, I=256, H=512, O=256.
// R10: consolidation on validated components after R6-R9 experiments:
//  - scan: R5-EXACT structure (448-lane remote polls, parity dbuf memLDS,
//    in-wave swizzle reduce, __syncthreads, same fmaf order) with the
//    R7-VALIDATED qword-pair exchange: one 8B agent-scope atomic store and
//    one 8B atomic load per row per step (was 2x4B).  Simple reload loop
//    with s_sleep backoff after 24 tries (R7-proven).
//  - GEMM1 fuses the x hi/lo bf16 split into LDS staging with bitwise-
//    identical RNE math (verified vs k_split) -> 4096-block x-split pass
//    deleted (~30us + launch gap).
//  R9 lesson (FAILED absmax): counted in-flight inline-asm loads consumed by
//  C-level control flow are UB (compiler inserts phi copies before the
//  waitcnt). Only compiler-managed atomic loads are safe for the poll.
//  R6 lesson: sc0 loads don't bypass L1 -> stale spin. R7 lesson: 8x poll
//  duplication congests the LLC. R8 lesson: L2 fast-rail never validates.

#define T_STEPS 512
#define BATCH 64
#define HID 512
#define IN_DIM 256
#define OUT_DIM 256
#define BETA 0.9f
#define THR 1.0f
#define SENT 0x7FC00000u

typedef __attribute__((ext_vector_type(8))) short short8;
typedef __attribute__((ext_vector_type(4))) float float4v;
typedef unsigned short ushort_t;
typedef unsigned long long u64_t;

// ---------------------------------------------------------------- NaN fill
__global__ __launch_bounds__(256) void k_fill_nan(uint32_t* __restrict__ P) {
  const int idx = blockIdx.x * 256 + threadIdx.x;  // 65536 threads
  uint4 s = make_uint4(SENT, SENT, SENT, SENT);
  uint4* p4 = (uint4*)P;
  for (int i = idx; i < (32768 * 512) / 4; i += 65536) p4[i] = s;
}

// ---------------------------------------------------------------- fp32 -> hi/lo bf16 split
__global__ __launch_bounds__(256) void k_split(const float* __restrict__ src,
                                               ushort_t* __restrict__ hi,
                                               ushort_t* __restrict__ lo, int n) {
  int i = blockIdx.x * 256 + threadIdx.x;
  const int stride = gridDim.x * 256;
  for (; i < n; i += stride) {
    float v = src[i];
    uint32_t u = __float_as_uint(v);
    uint32_t rh = u + 0x7FFFu + ((u >> 16) & 1u);   // RNE to bf16
    ushort_t h = (ushort_t)(rh >> 16);
    float hf = __uint_as_float(((uint32_t)h) << 16);
    float l = v - hf;
    uint32_t ul = __float_as_uint(l);
    uint32_t rl = ul + 0x7FFFu + ((ul >> 16) & 1u);
    hi[i] = h;
    lo[i] = (ushort_t)(rl >> 16);
  }
}

// split helpers (bitwise-identical math to k_split), 2 elems -> packed u32
__device__ __forceinline__ uint32_t rne_hi2(uint32_t ua, uint32_t ub) {
  uint32_t ra = ua + 0x7FFFu + ((ua >> 16) & 1u);
  uint32_t rb = ub + 0x7FFFu + ((ub >> 16) & 1u);
  return (ra >> 16) | (rb & 0xFFFF0000u);
}
__device__ __forceinline__ uint32_t rne_lo2(uint32_t ua, uint32_t ub) {
  uint32_t ra = ua + 0x7FFFu + ((ua >> 16) & 1u);
  uint32_t rb = ub + 0x7FFFu + ((ub >> 16) & 1u);
  float la = __uint_as_float(ua) - __uint_as_float(ra & 0xFFFF0000u);
  float lb = __uint_as_float(ub) - __uint_as_float(rb & 0xFFFF0000u);
  uint32_t ula = __float_as_uint(la), ulb = __float_as_uint(lb);
  uint32_t rla = ula + 0x7FFFu + ((ula >> 16) & 1u);
  uint32_t rlb = ulb + 0x7FFFu + ((ulb >> 16) & 1u);
  return (rla >> 16) | (rlb & 0xFFFF0000u);
}

// ---------------------------------------------------------------- softmax over t
__global__ __launch_bounds__(256) void k_softmax_t(
    const float* __restrict__ TA, float* __restrict__ attn) {
  __shared__ float redm[8][32];
  __shared__ float reds[8][32];
  const int ol = threadIdx.x & 31;
  const int tg = threadIdx.x >> 5;
  const int o = blockIdx.x * 32 + ol;
  float mx = -1e30f;
  for (int i = 0; i < 64; ++i) {
    float v = TA[(size_t)(tg * 64 + i) * OUT_DIM + o];
    mx = fmaxf(mx, v);
  }
  redm[tg][ol] = mx;
  __syncthreads();
  float m = redm[0][ol];
#pragma unroll
  for (int j = 1; j < 8; ++j) m = fmaxf(m, redm[j][ol]);
  float s = 0.f;
  for (int i = 0; i < 64; ++i) {
    float v = TA[(size_t)(tg * 64 + i) * OUT_DIM + o];
    s += __expf(v - m);
  }
  reds[tg][ol] = s;
  __syncthreads();
  float tot = 0.f;
#pragma unroll
  for (int j = 0; j < 8; ++j) tot += reds[j][ol];
  const float inv = 1.0f / tot;
  for (int i = 0; i < 64; ++i) {
    int t = tg * 64 + i;
    float v = TA[(size_t)t * OUT_DIM + o];
    attn[(size_t)t * OUT_DIM + o] = __expf(v - m) * inv;
  }
}

// ---------------------------------------------------------------- MFMA GEMM, fused-split A (x fp32), 3-term
// C = (Ahi+Alo)(Bhi+Blo)^T + bias, dropping lo*lo. A split happens during LDS
// staging with bitwise-identical RNE math -> same result as pre-split path.
__global__ __launch_bounds__(256) void k_gemm_fsplit3(
    const float* __restrict__ A, const ushort_t* __restrict__ Bhi,
    const ushort_t* __restrict__ Blo, const float* __restrict__ bias,
    float* __restrict__ C, int M, int N, int K) {
  __shared__ ushort_t At[2][128 * 40];
  __shared__ ushort_t Bt[2][128 * 40];
  const int tid = threadIdx.x;
  const int row0 = blockIdx.x * 128, col0 = blockIdx.y * 128;
  const int w = tid >> 6, lane = tid & 63;
  const int wm = (w >> 1) * 64, wn = (w & 1) * 64;
  const int l15 = lane & 15, quad = lane >> 4;
  float4v acc[4][4];
#pragma unroll
  for (int i = 0; i < 4; ++i)
#pragma unroll
    for (int j = 0; j < 4; ++j) acc[i][j] = (float4v){0.f, 0.f, 0.f, 0.f};

  for (int k0 = 0; k0 < K; k0 += 32) {
#pragma unroll
    for (int it = 0; it < 2; ++it) {
      int idx = it * 256 + tid;          // 0..511
      int r = idx >> 2;                  // row 0..127
      int c8 = (idx & 3) << 3;           // k-offset {0,8,16,24}
      const float* ap_ = &A[(size_t)(row0 + r) * K + k0 + c8];
      uint4 f0 = *(const uint4*)ap_;
      uint4 f1 = *(const uint4*)(ap_ + 4);
      uint4 hi4, lo4;
      hi4.x = rne_hi2(f0.x, f0.y); lo4.x = rne_lo2(f0.x, f0.y);
      hi4.y = rne_hi2(f0.z, f0.w); lo4.y = rne_lo2(f0.z, f0.w);
      hi4.z = rne_hi2(f1.x, f1.y); lo4.z = rne_lo2(f1.x, f1.y);
      hi4.w = rne_hi2(f1.z, f1.w); lo4.w = rne_lo2(f1.z, f1.w);
      *(uint4*)(&At[0][r * 40 + c8]) = hi4;
      *(uint4*)(&At[1][r * 40 + c8]) = lo4;
      *(uint4*)(&Bt[0][r * 40 + c8]) =
          *(const uint4*)(&Bhi[(size_t)(col0 + r) * K + k0 + c8]);
      *(uint4*)(&Bt[1][r * 40 + c8]) =
          *(const uint4*)(&Blo[(size_t)(col0 + r) * K + k0 + c8]);
    }
    __syncthreads();
    short8 ah[4], al[4], bh[4], bl[4];
    const int koff = quad * 8;
#pragma unroll
    for (int i = 0; i < 4; ++i) {
      ah[i] = *(const short8*)(&At[0][(wm + i * 16 + l15) * 40 + koff]);
      al[i] = *(const short8*)(&At[1][(wm + i * 16 + l15) * 40 + koff]);
      bh[i] = *(const short8*)(&Bt[0][(wn + i * 16 + l15) * 40 + koff]);
      bl[i] = *(const short8*)(&Bt[1][(wn + i * 16 + l15) * 40 + koff]);
    }
#pragma unroll
    for (int i = 0; i < 4; ++i)
#pragma unroll
      for (int j = 0; j < 4; ++j) {
        acc[i][j] = __builtin_amdgcn_mfma_f32_16x16x32_bf16(ah[i], bh[j], acc[i][j], 0, 0, 0);
        acc[i][j] = __builtin_amdgcn_mfma_f32_16x16x32_bf16(ah[i], bl[j], acc[i][j], 0, 0, 0);
        acc[i][j] = __builtin_amdgcn_mfma_f32_16x16x32_bf16(al[i], bh[j], acc[i][j], 0, 0, 0);
      }
    __syncthreads();
  }
#pragma unroll
  for (int j = 0; j < 4; ++j) {
    const int col = col0 + wn + j * 16 + l15;
    const float bv = bias ? bias[col] : 0.f;
#pragma unroll
    for (int i = 0; i < 4; ++i) {
#pragma unroll
      for (int r = 0; r < 4; ++r) {
        int row = row0 + wm + i * 16 + quad * 4 + r;
        C[(size_t)row * N + col] = acc[i][j][r] + bv;
      }
    }
  }
}

// ---------------------------------------------------------------- MFMA GEMM, spike-A 2-term
__global__ __launch_bounds__(256) void k_gemm_spike2(
    const float* __restrict__ A, const ushort_t* __restrict__ Bhi,
    const ushort_t* __restrict__ Blo, const float* __restrict__ bias,
    float* __restrict__ C, int M, int N, int K) {
  __shared__ ushort_t At[128 * 72];
  __shared__ ushort_t Bt[2][128 * 72];
  const int tid = threadIdx.x;
  const int row0 = blockIdx.x * 128, col0 = blockIdx.y * 128;
  const int w = tid >> 6, lane = tid & 63;
  const int wm = (w >> 1) * 64, wn = (w & 1) * 64;
  const int l15 = lane & 15, quad = lane >> 4;
  float4v acc[4][4];
#pragma unroll
  for (int i = 0; i < 4; ++i)
#pragma unroll
    for (int j = 0; j < 4; ++j) acc[i][j] = (float4v){0.f, 0.f, 0.f, 0.f};

  for (int k0 = 0; k0 < K; k0 += 64) {
#pragma unroll
    for (int it = 0; it < 4; ++it) {
      int idx = it * 256 + tid;          // 0..1023
      int r = idx >> 3;                  // row 0..127
      int c8 = (idx & 7) << 3;           // k-offset 0..56 step 8
      uint4 pa = *(const uint4*)(&A[(size_t)(row0 + r) * K + k0 + c8]);
      uint4 pb = *(const uint4*)(&A[(size_t)(row0 + r) * K + k0 + c8 + 4]);
      uint4 st;
      st.x = (pa.x >> 16) | (pa.y & 0xFFFF0000u);
      st.y = (pa.z >> 16) | (pa.w & 0xFFFF0000u);
      st.z = (pb.x >> 16) | (pb.y & 0xFFFF0000u);
      st.w = (pb.z >> 16) | (pb.w & 0xFFFF0000u);
      *(uint4*)(&At[r * 72 + c8]) = st;
      *(uint4*)(&Bt[0][r * 72 + c8]) =
          *(const uint4*)(&Bhi[(size_t)(col0 + r) * K + k0 + c8]);
      *(uint4*)(&Bt[1][r * 72 + c8]) =
          *(const uint4*)(&Blo[(size_t)(col0 + r) * K + k0 + c8]);
    }
    __syncthreads();
#pragma unroll
    for (int ks = 0; ks < 2; ++ks) {
      short8 a[4], bh[4], bl[4];
      const int koff = ks * 32 + quad * 8;
#pragma unroll
      for (int i = 0; i < 4; ++i) {
        a[i] = *(const short8*)(&At[(wm + i * 16 + l15) * 72 + koff]);
        bh[i] = *(const short8*)(&Bt[0][(wn + i * 16 + l15) * 72 + koff]);
        bl[i] = *(const short8*)(&Bt[1][(wn + i * 16 + l15) * 72 + koff]);
      }
#pragma unroll
      for (int i = 0; i < 4; ++i)
#pragma unroll
        for (int j = 0; j < 4; ++j) {
          acc[i][j] = __builtin_amdgcn_mfma_f32_16x16x32_bf16(a[i], bh[j], acc[i][j], 0, 0, 0);
          acc[i][j] = __builtin_amdgcn_mfma_f32_16x16x32_bf16(a[i], bl[j], acc[i][j], 0, 0, 0);
        }
    }
    __syncthreads();
  }
#pragma unroll
  for (int j = 0; j < 4; ++j) {
    const int col = col0 + wn + j * 16 + l15;
    const float bv = bias ? bias[col] : 0.f;
#pragma unroll
    for (int i = 0; i < 4; ++i) {
#pragma unroll
      for (int r = 0; r < 4; ++r) {
        int row = row0 + wm + i * 16 + quad * 4 + r;
        C[(size_t)row * N + col] = acc[i][j][r] + bv;
      }
    }
  }
}

// ---------------------------------------------------------------- LIF scan #1
__global__ __launch_bounds__(256) void k_lif1(float* __restrict__ p) {
  const int id = blockIdx.x * 256 + threadIdx.x;  // 0..32767
  const size_t base = (size_t)(id >> 9) * (T_STEPS * HID) + (id & 511);
  float mem = 0.f;
  for (int t0 = 0; t0 < T_STEPS; t0 += 8) {
    float v[8];
#pragma unroll
    for (int j = 0; j < 8; ++j) v[j] = p[base + (size_t)(t0 + j) * HID];
#pragma unroll
    for (int j = 0; j < 8; ++j) {
      float nm = BETA * mem + v[j];
      float sp = nm > THR ? 1.0f : 0.0f;
      p[base + (size_t)(t0 + j) * HID] = sp;
      mem = nm - sp;
    }
  }
}

// ---------------------------------------------------------------- recurrent scan (R10)
// R5-exact structure; exchange is qword pairs (R7-validated): P[t][grp][row]
// holds (mem0,mem1) as one 8B value, agent-scope relaxed atomics both ways.
__global__ __launch_bounds__(512) void k_recurrent_cp(
    const float* __restrict__ W, const float* __restrict__ b_hh,
    float* __restrict__ rp, float* __restrict__ P) {
  const int tid = threadIdx.x;
  const int grp = blockIdx.x & 31;  // stride-32 members: same XCD under %8 RR
  const int j   = blockIdx.x >> 5;  // output-column block 0..7
  const int w   = tid >> 6;         // wave 0..7
  const int l   = tid & 63;
  const int q   = l >> 3;           // row-in-group 0..7
  const int c   = l & 7;            // k-chunk of this lane
  const int row = (w << 3) + q;     // 0..63 output row within block
  const int g0  = j << 6;

  __shared__ float memLDS[2][2][8 * 72];  // [parity][ob][chunk*72 + k]

  for (int i = tid; i < 2 * 2 * 8 * 72; i += 512) ((float*)memLDS)[i] = 0.f;

  float Wreg[64];
  {
    const float* wrow = W + (size_t)(g0 + row) * HID + (c << 6);
#pragma unroll
    for (int k4 = 0; k4 < 16; ++k4) {
      float4 w4 = *(const float4*)(wrow + 4 * k4);
      Wreg[4 * k4 + 0] = w4.x; Wreg[4 * k4 + 1] = w4.y;
      Wreg[4 * k4 + 2] = w4.z; Wreg[4 * k4 + 3] = w4.w;
    }
  }

  const bool lif = (c == 0);
  const int og = g0 + row;
  const size_t rp_b0 = (size_t)(grp * 2 + 0) * (T_STEPS * HID) + og;
  const size_t rp_b1 = (size_t)(grp * 2 + 1) * (T_STEPS * HID) + og;
  const float bhh_v = lif ? b_hh[og] : 0.f;
  float mem0 = 0.f, mem1 = 0.f;     // membrane registers (valid on lif lanes)

  const int rg = (tid < g0) ? tid : tid + 64;        // remote row (tid<448)
  const int raddr = (rg >> 6) * 72 + (rg & 63);

  u64_t* Pq = (u64_t*)P;

  __syncthreads();

  for (int t = 0; t < T_STEPS; ++t) {
    const int par = t & 1;
    float ip0 = 0.f, ip1 = 0.f;
    if (lif) {
      ip0 = rp[rp_b0 + (size_t)t * HID];
      ip1 = rp[rp_b1 + (size_t)t * HID];
    }
    if (t > 0 && tid < 448) {
      const u64_t* ap = Pq + ((size_t)(t - 1) * 32 + grp) * 512 + rg;
      u64_t u = __hip_atomic_load(ap, __ATOMIC_RELAXED, __HIP_MEMORY_SCOPE_AGENT);
      int tries = 0;
      while (((uint32_t)u == SENT) || ((uint32_t)(u >> 32) == SENT)) {
        if (++tries > 24) __builtin_amdgcn_s_sleep(1);
        u = __hip_atomic_load(ap, __ATOMIC_RELAXED, __HIP_MEMORY_SCOPE_AGENT);
      }
      memLDS[par][0][raddr] = __uint_as_float((uint32_t)u);
      memLDS[par][1][raddr] = __uint_as_float((uint32_t)(u >> 32));
    }
    __syncthreads();

    float p0a = 0.f, p0b = 0.f, p1a = 0.f, p1b = 0.f;
    {
      const float4* m0 = (const float4*)&memLDS[par][0][c * 72];
      const float4* m1 = (const float4*)&memLDS[par][1][c * 72];
#pragma unroll
      for (int k4 = 0; k4 < 16; ++k4) {
        float4 a = m0[k4];
        float4 b = m1[k4];
        p0a = fmaf(Wreg[4 * k4 + 0], a.x, p0a);
        p0b = fmaf(Wreg[4 * k4 + 1], a.y, p0b);
        p0a = fmaf(Wreg[4 * k4 + 2], a.z, p0a);
        p0b = fmaf(Wreg[4 * k4 + 3], a.w, p0b);
        p1a = fmaf(Wreg[4 * k4 + 0], b.x, p1a);
        p1b = fmaf(Wreg[4 * k4 + 1], b.y, p1b);
        p1a = fmaf(Wreg[4 * k4 + 2], b.z, p1a);
        p1b = fmaf(Wreg[4 * k4 + 3], b.w, p1b);
      }
    }
    const int i0 = __float_as_int(p0a + p0b);
    const int i1 = __float_as_int(p1a + p1b);
    // serial ascending-chunk reduce across lanes (l&56)+ss  (== old scratch)
    float s0 = 0.f, s1 = 0.f;
#define RED(ss)                                                                 \
    s0 += __int_as_float(__builtin_amdgcn_ds_swizzle(i0, ((ss) << 5) | 0x18)); \
    s1 += __int_as_float(__builtin_amdgcn_ds_swizzle(i1, ((ss) << 5) | 0x18));
    RED(0) RED(1) RED(2) RED(3) RED(4) RED(5) RED(6) RED(7)
#undef RED

    if (lif) {
      const int npar = par ^ 1;
      const float nm0 = BETA * mem0 + ip0 + s0 + bhh_v;
      const float sp0 = nm0 > THR ? 1.0f : 0.0f;
      mem0 = nm0 - sp0;
      const float nm1 = BETA * mem1 + ip1 + s1 + bhh_v;
      const float sp1 = nm1 > THR ? 1.0f : 0.0f;
      mem1 = nm1 - sp1;
      const u64_t pk =
          ((u64_t)__float_as_uint(mem1) << 32) | (u64_t)__float_as_uint(mem0);
      __hip_atomic_store(Pq + ((size_t)t * 32 + grp) * 512 + og, pk,
                         __ATOMIC_RELAXED, __HIP_MEMORY_SCOPE_AGENT);
      rp[rp_b0 + (size_t)t * HID] = sp0;
      rp[rp_b1 + (size_t)t * HID] = sp1;
      memLDS[npar][0][j * 72 + row] = mem0;
      memLDS[npar][1][j * 72 + row] = mem1;
    }
  }
}

// ---------------------------------------------------------------- attend + threshold
__global__ __launch_bounds__(256) void k_attend(
    const float* __restrict__ op, const float* __restrict__ attn,
    const float* __restrict__ b_out, float* __restrict__ out) {
  const int b = blockIdx.x;
  const int o = threadIdx.x;
  float s = b_out[o];
  const float* opb = op + (size_t)b * T_STEPS * OUT_DIM + o;
  for (int t0 = 0; t0 < T_STEPS; t0 += 8) {
    float av[8], pv[8];
#pragma unroll
    for (int j = 0; j < 8; ++j) {
      av[j] = attn[(size_t)(t0 + j) * OUT_DIM + o];
      pv[j] = opb[(size_t)(t0 + j) * OUT_DIM];
    }
#pragma unroll
    for (int j = 0; j < 8; ++j) s = fmaf(av[j], pv[j], s);
  }
  out[b * OUT_DIM + o] = s > THR ? 1.0f : 0.0f;
}

// ---------------------------------------------------------------- launch
extern "C" void kernel_launch(void* const* d_in, const int* in_sizes, int n_in,
                              void* d_out, int out_size, void* d_ws, size_t ws_size,
                              hipStream_t stream) {
  (void)in_sizes; (void)n_in; (void)out_size; (void)ws_size;
  const float* x     = (const float*)d_in[0];
  const float* W_in  = (const float*)d_in[1];
  const float* b_in  = (const float*)d_in[2];
  const float* W_ih  = (const float*)d_in[3];
  const float* b_ih  = (const float*)d_in[4];
  const float* W_hh  = (const float*)d_in[5];
  const float* b_hh  = (const float*)d_in[6];
  const float* W_out = (const float*)d_in[7];
  const float* b_out = (const float*)d_in[8];
  const float* TA    = (const float*)d_in[9];

  float* ws = (float*)d_ws;
  float* proj  = ws;                           // 16.78M floats: GEMM1 out / P / out_proj
  float* rproj = proj + (size_t)32768 * 512;   // 16.78M floats: GEMM2 out
  float* attn  = rproj + (size_t)32768 * 512;  // 131072 floats
  ushort_t* wih_hi = (ushort_t*)(attn + 512 * 256);
  ushort_t* wih_lo = wih_hi + 512 * 512;
  ushort_t* win_hi = wih_lo + 512 * 512;
  ushort_t* win_lo = win_hi + 512 * 256;
  ushort_t* wout_hi = win_lo + 512 * 256;
  ushort_t* wout_lo = wout_hi + 256 * 512;
  float* P = proj;            // exchange slots [t][grp][row] qword pairs
  float* out_proj = proj;     // (b*T, O) fp32, written after recurrent

  k_softmax_t<<<8, 256, 0, stream>>>(TA, attn);
  k_split<<<512, 256, 0, stream>>>(W_in, win_hi, win_lo, 512 * 256);
  k_split<<<512, 256, 0, stream>>>(W_ih, wih_hi, wih_lo, 512 * 512);
  k_split<<<512, 256, 0, stream>>>(W_out, wout_hi, wout_lo, 256 * 512);

  // GEMM1: proj = x @ W_in^T + b_in   (M=32768, N=512, K=256), x split fused
  k_gemm_fsplit3<<<dim3(256, 4), 256, 0, stream>>>(
      x, win_hi, win_lo, b_in, proj, 32768, 512, 256);
  k_lif1<<<128, 256, 0, stream>>>(proj);
  // GEMM2: rproj = spikes @ W_ih^T + b_ih   (M=32768, N=512, K=512)
  k_gemm_spike2<<<dim3(256, 4), 256, 0, stream>>>(
      proj, wih_hi, wih_lo, b_ih, rproj, 32768, 512, 512);
  k_fill_nan<<<256, 256, 0, stream>>>((uint32_t*)P);  // proj dead after GEMM2
  k_recurrent_cp<<<256, 512, 0, stream>>>(W_hh, b_hh, rproj, P);
  // GEMM3: out_proj = tspikes @ W_out^T   (M=32768, N=256, K=512, no bias)
  k_gemm_spike2<<<dim3(256, 2), 256, 0, stream>>>(
      rproj, wout_hi, wout_lo, nullptr, out_proj, 32768, 256, 512);
  k_attend<<<64, 256, 0, stream>>>(out_proj, attn, b_out, (float*)d_out);
}